// Round 1
// baseline (682.982 us; speedup 1.0000x reference)
//
#include <hip/hip_runtime.h>

// Problem constants (fixed by reference): B=64, T=4096, D=512, fp32.
constexpr int B = 64;
constexpr int T = 4096;
constexpr int D = 512;
constexpr int CHUNKS = 16;                    // blocks per batch row
constexpr int ROWS_PER_CHUNK = T / CHUNKS;    // 256 t-rows per block
constexpr int PART_STRIDE = D + 2;            // [m, l, o[512]] per partial

// ---------------------------------------------------------------------------
// Pass 1: fused GEMV-scores + online-softmax accumulation.
// Grid: B*CHUNKS blocks of 256 threads (4 waves). Each wave processes rows
// t = chunk*256 + wave + 4k. Lane i owns d in [4i,4i+4) and [256+4i,256+4i+4)
// -> two coalesced float4 loads per row per lane (2 KiB per wave-row).
// Raw energies are written into the d_out weights region (transformed to
// softmax weights in-place by pass 2). One (m,l,o[D]) partial per block -> ws.
// ---------------------------------------------------------------------------
__global__ __launch_bounds__(256) void attn_pass1(
    const float* __restrict__ enc,        // [B, T, D]
    const float* __restrict__ v,          // [D]
    float* __restrict__ energies,         // [B, T]  (d_out weights region)
    float* __restrict__ partials)         // [B*CHUNKS, PART_STRIDE]
{
    const int blk   = blockIdx.x;
    const int b     = blk / CHUNKS;
    const int chunk = blk % CHUNKS;
    const int tid   = threadIdx.x;
    const int wave  = tid >> 6;
    const int lane  = tid & 63;

    // v fragment for this lane (loaded once)
    const float4 v0 = *(const float4*)(v + lane * 4);
    const float4 v1 = *(const float4*)(v + 256 + lane * 4);

    float  m = -3.0e38f;
    float  l = 0.0f;
    float4 o0 = make_float4(0.f, 0.f, 0.f, 0.f);
    float4 o1 = make_float4(0.f, 0.f, 0.f, 0.f);

    const int t0 = chunk * ROWS_PER_CHUNK;
    const float* encb = enc + (size_t)b * T * D;

    for (int k = 0; k < ROWS_PER_CHUNK / 4; ++k) {
        const int t = t0 + wave + 4 * k;
        const float* row = encb + (size_t)t * D;
        const float4 a0 = *(const float4*)(row + lane * 4);
        const float4 a1 = *(const float4*)(row + 256 + lane * 4);

        // partial dot
        float e = a0.x * v0.x + a0.y * v0.y + a0.z * v0.z + a0.w * v0.w
                + a1.x * v1.x + a1.y * v1.y + a1.z * v1.z + a1.w * v1.w;
        // wave-wide sum (64 lanes), butterfly so all lanes hold e
        #pragma unroll
        for (int off = 32; off > 0; off >>= 1)
            e += __shfl_xor(e, off, 64);

        if (lane == 0) energies[(size_t)b * T + t] = e;

        // online softmax update
        const float m_new = fmaxf(m, e);
        const float corr  = __expf(m - m_new);   // 0 on first iter (m=-3e38)
        const float p     = __expf(e - m_new);
        l = l * corr + p;
        o0.x = o0.x * corr + p * a0.x;
        o0.y = o0.y * corr + p * a0.y;
        o0.z = o0.z * corr + p * a0.z;
        o0.w = o0.w * corr + p * a0.w;
        o1.x = o1.x * corr + p * a1.x;
        o1.y = o1.y * corr + p * a1.y;
        o1.z = o1.z * corr + p * a1.z;
        o1.w = o1.w * corr + p * a1.w;
        m = m_new;
    }

    // ---- combine the 4 waves of this block ----
    __shared__ float sm[4];
    __shared__ float sl[4];
    __shared__ float so[4][D];   // 8 KiB

    if (lane == 0) { sm[wave] = m; sl[wave] = l; }
    *(float4*)&so[wave][lane * 4]       = o0;
    *(float4*)&so[wave][256 + lane * 4] = o1;
    __syncthreads();

    const float m_blk = fmaxf(fmaxf(sm[0], sm[1]), fmaxf(sm[2], sm[3]));
    const float s0 = __expf(sm[0] - m_blk);
    const float s1 = __expf(sm[1] - m_blk);
    const float s2 = __expf(sm[2] - m_blk);
    const float s3 = __expf(sm[3] - m_blk);
    const float l_blk = sl[0] * s0 + sl[1] * s1 + sl[2] * s2 + sl[3] * s3;

    float* part = partials + (size_t)blk * PART_STRIDE;
    if (tid == 0) { part[0] = m_blk; part[1] = l_blk; }
    for (int d = tid; d < D; d += 256) {
        part[2 + d] = so[0][d] * s0 + so[1][d] * s1
                    + so[2][d] * s2 + so[3][d] * s3;
    }
}

// ---------------------------------------------------------------------------
// Pass 2: per batch, reduce the 16 chunk partials -> global (m, l);
// write context[b, :]; transform energies -> softmax weights in place.
// Traffic ~4 MB total, negligible.
// ---------------------------------------------------------------------------
__global__ __launch_bounds__(256) void attn_pass2(
    const float* __restrict__ partials,   // [B*CHUNKS, PART_STRIDE]
    float* __restrict__ ctx,              // [B, D] (d_out head)
    float* __restrict__ weights)          // [B, T] (in-place energies)
{
    const int b   = blockIdx.x;
    const int tid = threadIdx.x;
    const float* pb = partials + (size_t)b * CHUNKS * PART_STRIDE;

    // every thread computes the (tiny) global stats redundantly
    float m_g = -3.0e38f;
    #pragma unroll
    for (int c = 0; c < CHUNKS; ++c)
        m_g = fmaxf(m_g, pb[c * PART_STRIDE]);

    float sc[CHUNKS];
    float l_g = 0.0f;
    #pragma unroll
    for (int c = 0; c < CHUNKS; ++c) {
        const float s = __expf(pb[c * PART_STRIDE] - m_g);
        sc[c] = s;
        l_g += pb[c * PART_STRIDE + 1] * s;
    }
    const float inv_l = 1.0f / l_g;

    // context
    for (int d = tid; d < D; d += 256) {
        float acc = 0.0f;
        #pragma unroll
        for (int c = 0; c < CHUNKS; ++c)
            acc += pb[c * PART_STRIDE + 2 + d] * sc[c];
        ctx[(size_t)b * D + d] = acc * inv_l;
    }

    // energies -> weights, in place (each thread owns its elements; no race)
    float* wrow = weights + (size_t)b * T;
    for (int t = tid; t < T; t += 256) {
        wrow[t] = __expf(wrow[t] - m_g) * inv_l;
    }
}

extern "C" void kernel_launch(void* const* d_in, const int* in_sizes, int n_in,
                              void* d_out, int out_size, void* d_ws, size_t ws_size,
                              hipStream_t stream) {
    const float* enc = (const float*)d_in[0];   // [B,T,D] fp32
    const float* v   = (const float*)d_in[1];   // [D,1]   fp32
    float* out     = (float*)d_out;
    float* ctx     = out;            // first B*D floats
    float* weights = out + B * D;    // next  B*T floats (also energy scratch)
    float* partials = (float*)d_ws;  // needs B*CHUNKS*PART_STRIDE*4 ≈ 2.06 MB

    attn_pass1<<<B * CHUNKS, 256, 0, stream>>>(enc, v, weights, partials);
    attn_pass2<<<B, 256, 0, stream>>>(partials, ctx, weights);
}

// Round 2
// 682.925 us; speedup vs baseline: 1.0001x; 1.0001x over previous
//
#include <hip/hip_runtime.h>

// Problem constants (fixed by reference): B=64, T=4096, D=512, fp32.
constexpr int B = 64;
constexpr int T = 4096;
constexpr int D = 512;
constexpr int CHUNKS = 16;                    // blocks per batch row
constexpr int ROWS_PER_CHUNK = T / CHUNKS;    // 256 t-rows per block
constexpr int PART_STRIDE = D + 2;            // [m, l, o[512]] per partial

__device__ __forceinline__ float dot8(const float4& a0, const float4& v0,
                                      const float4& a1, const float4& v1) {
    return a0.x * v0.x + a0.y * v0.y + a0.z * v0.z + a0.w * v0.w
         + a1.x * v1.x + a1.y * v1.y + a1.z * v1.z + a1.w * v1.w;
}

// ---------------------------------------------------------------------------
// Pass 1: fused GEMV-scores + online-softmax accumulation.
// Grid: B*CHUNKS blocks of 256 threads (4 waves). Per iteration each wave
// processes 4 CONSECUTIVE rows (8 float4 loads in flight, 4 independent
// butterfly-reduce chains, ONE corr/rescale per 4 rows). Lane i owns
// d in [4i,4i+4) and [256+4i,256+4i+4) -> coalesced 1 KiB segments.
// ---------------------------------------------------------------------------
__global__ __launch_bounds__(256) void attn_pass1(
    const float* __restrict__ enc,        // [B, T, D]
    const float* __restrict__ v,          // [D]
    float* __restrict__ energies,         // [B, T]  (d_out weights region)
    float* __restrict__ partials)         // [B*CHUNKS, PART_STRIDE]
{
    const int blk   = blockIdx.x;
    const int b     = blk / CHUNKS;
    const int chunk = blk % CHUNKS;
    const int tid   = threadIdx.x;
    const int wave  = tid >> 6;
    const int lane  = tid & 63;

    const float4 v0 = *(const float4*)(v + lane * 4);
    const float4 v1 = *(const float4*)(v + 256 + lane * 4);

    float  m = -3.0e38f;
    float  l = 0.0f;
    float4 o0 = make_float4(0.f, 0.f, 0.f, 0.f);
    float4 o1 = make_float4(0.f, 0.f, 0.f, 0.f);

    const int t0 = chunk * ROWS_PER_CHUNK;
    const float* encb = enc + (size_t)b * T * D;

    for (int k = 0; k < ROWS_PER_CHUNK / 16; ++k) {
        const int t = t0 + k * 16 + wave * 4;      // 4 consecutive rows
        const float* row = encb + (size_t)t * D;

        float4 a0[4], a1[4];
        #pragma unroll
        for (int r = 0; r < 4; ++r) {
            a0[r] = *(const float4*)(row + r * D + lane * 4);
            a1[r] = *(const float4*)(row + r * D + 256 + lane * 4);
        }

        float e[4];
        #pragma unroll
        for (int r = 0; r < 4; ++r)
            e[r] = dot8(a0[r], v0, a1[r], v1);

        // 4 independent 64-lane butterfly reductions (ILP)
        #pragma unroll
        for (int off = 32; off > 0; off >>= 1) {
            #pragma unroll
            for (int r = 0; r < 4; ++r)
                e[r] += __shfl_xor(e[r], off, 64);
        }

        if (lane == 0)
            *(float4*)(energies + (size_t)b * T + t) =
                make_float4(e[0], e[1], e[2], e[3]);

        // one online-softmax update per 4 rows
        float m_new = m;
        #pragma unroll
        for (int r = 0; r < 4; ++r) m_new = fmaxf(m_new, e[r]);
        const float corr = __expf(m - m_new);   // exp(-3e38)=0 on first iter
        float p[4];
        #pragma unroll
        for (int r = 0; r < 4; ++r) p[r] = __expf(e[r] - m_new);
        l = l * corr + p[0] + p[1] + p[2] + p[3];

        o0.x = o0.x * corr + p[0]*a0[0].x + p[1]*a0[1].x + p[2]*a0[2].x + p[3]*a0[3].x;
        o0.y = o0.y * corr + p[0]*a0[0].y + p[1]*a0[1].y + p[2]*a0[2].y + p[3]*a0[3].y;
        o0.z = o0.z * corr + p[0]*a0[0].z + p[1]*a0[1].z + p[2]*a0[2].z + p[3]*a0[3].z;
        o0.w = o0.w * corr + p[0]*a0[0].w + p[1]*a0[1].w + p[2]*a0[2].w + p[3]*a0[3].w;
        o1.x = o1.x * corr + p[0]*a1[0].x + p[1]*a1[1].x + p[2]*a1[2].x + p[3]*a1[3].x;
        o1.y = o1.y * corr + p[0]*a1[0].y + p[1]*a1[1].y + p[2]*a1[2].y + p[3]*a1[3].y;
        o1.z = o1.z * corr + p[0]*a1[0].z + p[1]*a1[1].z + p[2]*a1[2].z + p[3]*a1[3].z;
        o1.w = o1.w * corr + p[0]*a1[0].w + p[1]*a1[1].w + p[2]*a1[2].w + p[3]*a1[3].w;
        m = m_new;
    }

    // ---- combine the 4 waves of this block ----
    __shared__ float sm[4];
    __shared__ float sl[4];
    __shared__ float so[4][D];   // 8 KiB

    if (lane == 0) { sm[wave] = m; sl[wave] = l; }
    *(float4*)&so[wave][lane * 4]       = o0;
    *(float4*)&so[wave][256 + lane * 4] = o1;
    __syncthreads();

    const float m_blk = fmaxf(fmaxf(sm[0], sm[1]), fmaxf(sm[2], sm[3]));
    const float s0 = __expf(sm[0] - m_blk);
    const float s1 = __expf(sm[1] - m_blk);
    const float s2 = __expf(sm[2] - m_blk);
    const float s3 = __expf(sm[3] - m_blk);
    const float l_blk = sl[0] * s0 + sl[1] * s1 + sl[2] * s2 + sl[3] * s3;

    float* part = partials + (size_t)blk * PART_STRIDE;
    if (tid == 0) { part[0] = m_blk; part[1] = l_blk; }
    for (int d = tid; d < D; d += 256) {
        part[2 + d] = so[0][d] * s0 + so[1][d] * s1
                    + so[2][d] * s2 + so[3][d] * s3;
    }
}

// ---------------------------------------------------------------------------
// Pass 2: grid = B*4 blocks. Each block redundantly reduces its batch's 16
// chunk partials -> (m_g, l_g); slice 0 also writes ctx. Each block then
// transforms a 1024-element quarter of the weights row, float4-vectorized
// (256 thr x 4 elems, exact).
// ---------------------------------------------------------------------------
__global__ __launch_bounds__(256) void attn_pass2(
    const float* __restrict__ partials,   // [B*CHUNKS, PART_STRIDE]
    float* __restrict__ ctx,              // [B, D] (d_out head)
    float* __restrict__ weights)          // [B, T] (in-place energies)
{
    const int b     = blockIdx.x >> 2;
    const int slice = blockIdx.x & 3;
    const int tid   = threadIdx.x;
    const float* pb = partials + (size_t)b * CHUNKS * PART_STRIDE;

    float m_g = -3.0e38f;
    #pragma unroll
    for (int c = 0; c < CHUNKS; ++c)
        m_g = fmaxf(m_g, pb[c * PART_STRIDE]);

    float sc[CHUNKS];
    float l_g = 0.0f;
    #pragma unroll
    for (int c = 0; c < CHUNKS; ++c) {
        const float s = __expf(pb[c * PART_STRIDE] - m_g);
        sc[c] = s;
        l_g += pb[c * PART_STRIDE + 1] * s;
    }
    const float inv_l = 1.0f / l_g;

    if (slice == 0) {
        for (int d = tid; d < D; d += 256) {
            float acc = 0.0f;
            #pragma unroll
            for (int c = 0; c < CHUNKS; ++c)
                acc += pb[c * PART_STRIDE + 2 + d] * sc[c];
            ctx[(size_t)b * D + d] = acc * inv_l;
        }
    }

    // quarter-row weight transform, float4-vectorized
    float* wrow = weights + (size_t)b * T + slice * (T / 4);
    float4 w = *(float4*)(wrow + tid * 4);
    w.x = __expf(w.x - m_g) * inv_l;
    w.y = __expf(w.y - m_g) * inv_l;
    w.z = __expf(w.z - m_g) * inv_l;
    w.w = __expf(w.w - m_g) * inv_l;
    *(float4*)(wrow + tid * 4) = w;
}

extern "C" void kernel_launch(void* const* d_in, const int* in_sizes, int n_in,
                              void* d_out, int out_size, void* d_ws, size_t ws_size,
                              hipStream_t stream) {
    const float* enc = (const float*)d_in[0];   // [B,T,D] fp32
    const float* v   = (const float*)d_in[1];   // [D,1]   fp32
    float* out     = (float*)d_out;
    float* ctx     = out;            // first B*D floats
    float* weights = out + B * D;    // next  B*T floats (also energy scratch)
    float* partials = (float*)d_ws;  // B*CHUNKS*PART_STRIDE*4 ≈ 2.1 MB

    attn_pass1<<<B * CHUNKS, 256, 0, stream>>>(enc, v, weights, partials);
    attn_pass2<<<B * 4, 256, 0, stream>>>(partials, ctx, weights);
}